// Round 10
// baseline (620.223 us; speedup 1.0000x reference)
//
#include <hip/hip_runtime.h>
#include <hip/hip_cooperative_groups.h>
#include <stdint.h>

namespace cg = cooperative_groups;

// EdgeNetwork, round 15: ONE cooperative kernel (zero + msg + reduce).
// r14 post-mortem: fire-and-forget atomics = 136us, WRITE 160MB -- device-
// scope atomics bypass the non-coherent per-XCD L2s to the coherence point.
// Design space now mapped: r12 (memset -> msg 53 -> reduce ~15) is the best
// GPU pipeline; its 133.5 total contains ~60-78us NOT in our kernels
// (r14: 2 dispatches, gap 78; r12: 3 dispatches, gap 62 -> per-iteration
// boundary/flush/launch overhead, not per-dispatch-count).
// This round: fuse everything into one hipLaunchCooperativeKernel dispatch:
//  phase0 grid-strided zero of counts+oflow_acc -> fence+grid.sync
//  phase1 persistent r12 msg batches (wfrag prologue amortized ~2.5x;
//         1024 blocks co-resident -> 16 waves/CU GUARANTEED vs measured 10)
//  phase2 grid-strided r12 reduce (+oflow_acc add)
// Agent-scope fences around syncs handle cross-XCD msgs visibility.
// Fallback: r12 3-dispatch path if cooperative launch errors.
// History: r8/r12 133.0/133.5 (BEST) -> r13 191 (scatter RFO + gather lat)
// -> r14 216 (atomic write-through 160MB diagnosed).

constexpr int DIM  = 16;
constexpr int CAP  = 56;     // slots per atom; P(deg>=56) ~ 4e-5 at Poisson(32)
constexpr int CSTR = 16;     // counts stride (ints) = one 64B line per atom
constexpr int GPW  = 4;      // 16-edge groups per batch

using frag_ab = __attribute__((ext_vector_type(8))) short;   // 8 bf16
using frag_cd = __attribute__((ext_vector_type(4))) float;   // 4 f32
union ABPack { frag_ab f; uint32_t u[4]; };

__device__ __forceinline__ uint32_t pack_bf16_2(float lo, float hi) {
    return __builtin_amdgcn_perm(__float_as_uint(hi), __float_as_uint(lo), 0x07060302u);
}

// =================== shared device helpers (msg batch body) ===================
// Processes 4 groups starting at g0 for this wave. Identical to r12's body.
template <typename StoreTag = void>
__device__ __forceinline__ void msg_batch(
    const float* __restrict__ atom, const float* __restrict__ bond,
    const int*   __restrict__ pair,
    int* __restrict__ counts, float* __restrict__ oflow_acc,
    uint16_t* __restrict__ msgs, int n_edges, int g0,
    int lane, int col, int quad, int hb,
    const frag_ab (&wfrag)[8], const frag_ab& bias_a)
{
    // P1: pair loads (quad0 lanes only)
    int  ec_[GPW];
    int2 pr_[GPW];
#pragma unroll
    for (int u = 0; u < GPW; ++u) {
        const int e = ((g0 + u) << 4) + col;
        ec_[u] = min(e, n_edges - 1);
        pr_[u] = make_int2(0, 0);
        if (quad == 0) pr_[u] = ((const int2*)pair)[ec_[u]];
    }

    // src broadcast
    int src_[GPW];
#pragma unroll
    for (int u = 0; u < GPW; ++u) src_[u] = __shfl(pr_[u].y, col, 64);

    // P2: dedup gathers
    const int cq = ((quad & 1) << 1) | (quad >> 1);
    float4 am_[GPW], bm_[GPW];
#pragma unroll
    for (int u = 0; u < GPW; ++u) {
        am_[u] = *(const float4*)(atom + (size_t)src_[u] * DIM + cq * 4);
        bm_[u] = *(const float4*)(bond + (size_t)ec_[u] * DIM + quad * 4);
    }

    // P3: rank atomics (after gathers; consumed only at store time)
    int r_[GPW];
#pragma unroll
    for (int u = 0; u < GPW; ++u) {
        r_[u] = CAP;
        const int e = ((g0 + u) << 4) + col;
        if (quad == 0 && e < n_edges)
            r_[u] = atomicAdd(&counts[pr_[u].x * CSTR], 1);
    }

    // P4: per group: redistribute + pack + MFMA + store
#pragma unroll
    for (int u = 0; u < GPW; ++u) {
        float4 am = am_[u];
        float4 ao;
        ao.x = __shfl_xor(am.x, 32); ao.y = __shfl_xor(am.y, 32);
        ao.z = __shfl_xor(am.z, 32); ao.w = __shfl_xor(am.w, 32);
        float nb[8];
        nb[0] = quad < 2 ? am.x : ao.x;  nb[1] = quad < 2 ? am.y : ao.y;
        nb[2] = quad < 2 ? am.z : ao.z;  nb[3] = quad < 2 ? am.w : ao.w;
        nb[4] = quad < 2 ? ao.x : am.x;  nb[5] = quad < 2 ? ao.y : am.y;
        nb[6] = quad < 2 ? ao.z : am.z;  nb[7] = quad < 2 ? ao.w : am.w;

        float4 bm = bm_[u];
        float4 bo;
        bo.x = __shfl_xor(bm.x, 16); bo.y = __shfl_xor(bm.y, 16);
        bo.z = __shfl_xor(bm.z, 16); bo.w = __shfl_xor(bm.w, 16);
        float4 cA, cB;
        cA.x = (quad & 1) ? bo.x : bm.x; cA.y = (quad & 1) ? bo.y : bm.y;
        cA.z = (quad & 1) ? bo.z : bm.z; cA.w = (quad & 1) ? bo.w : bm.w;
        cB.x = (quad & 1) ? bm.x : bo.x; cB.y = (quad & 1) ? bm.y : bo.y;
        cB.z = (quad & 1) ? bm.z : bo.z; cB.w = (quad & 1) ? bm.w : bo.w;
        float s0 = hb ? cA.y : cA.x,  s1 = hb ? cA.w : cA.z;
        float s2 = hb ? cB.y : cB.x,  s3 = hb ? cB.w : cB.z;
        float g0v = hb ? cA.x : cA.y, g1v = hb ? cA.z : cA.w;
        float g2v = hb ? cB.x : cB.y, g3v = hb ? cB.z : cB.w;
        float t0 = __shfl_xor(g0v, 32), t1 = __shfl_xor(g1v, 32);
        float t2 = __shfl_xor(g2v, 32), t3 = __shfl_xor(g3v, 32);
        float bks[8];
        bks[0] = quad < 2 ? s0 : t0;  bks[1] = quad < 2 ? s1 : t1;
        bks[2] = quad < 2 ? s2 : t2;  bks[3] = quad < 2 ? s3 : t3;
        bks[4] = quad < 2 ? t0 : s0;  bks[5] = quad < 2 ? t1 : s1;
        bks[6] = quad < 2 ? t2 : s2;  bks[7] = quad < 2 ? t3 : s3;

        frag_cd acc0 = {0.f, 0.f, 0.f, 0.f};
        frag_cd acc1 = {0.f, 0.f, 0.f, 0.f};
#pragma unroll
        for (int c = 0; c < 8; ++c) {
            const float bk = bks[c];
            ABPack z;
            z.u[0] = pack_bf16_2(bk * nb[0], bk * nb[1]);
            z.u[1] = pack_bf16_2(bk * nb[2], bk * nb[3]);
            z.u[2] = pack_bf16_2(bk * nb[4], bk * nb[5]);
            z.u[3] = pack_bf16_2(bk * nb[6], bk * nb[7]);
            if (c & 1)
                acc1 = __builtin_amdgcn_mfma_f32_16x16x32_bf16(wfrag[c], z.f, acc1, 0, 0, 0);
            else
                acc0 = __builtin_amdgcn_mfma_f32_16x16x32_bf16(wfrag[c], z.f, acc0, 0, 0, 0);
        }
        {
            ABPack z; z.u[0] = z.u[1] = z.u[2] = z.u[3] = 0;
            if (hb == 0) {
                z.u[0] = pack_bf16_2(nb[0], nb[1]);
                z.u[1] = pack_bf16_2(nb[2], nb[3]);
                z.u[2] = pack_bf16_2(nb[4], nb[5]);
                z.u[3] = pack_bf16_2(nb[6], nb[7]);
            }
            acc1 = __builtin_amdgcn_mfma_f32_16x16x32_bf16(bias_a, z.f, acc1, 0, 0, 0);
        }
        frag_cd acc = acc0 + acc1;

        int slot = -1;
        const int e = ((g0 + u) << 4) + col;
        if (quad == 0 && e < n_edges && r_[u] < CAP)
            slot = pr_[u].x * CAP + r_[u];
        const int s    = __shfl(slot, col, 64);
        const int dstb = __shfl(pr_[u].x, col, 64);

        uint2 pkd;
        pkd.x = pack_bf16_2(acc[0], acc[1]);
        pkd.y = pack_bf16_2(acc[2], acc[3]);
        uint32_t qx = __shfl_xor(pkd.x, 16);
        uint32_t qy = __shfl_xor(pkd.y, 16);
        if (e < n_edges) {
            if (s >= 0) {
                if ((quad & 1) == 0) {
                    uint4 w4 = make_uint4(pkd.x, pkd.y, qx, qy);
                    *(uint4*)(msgs + (size_t)s * DIM + (quad & 2) * 4) = w4;
                }
            } else {
                atomicAdd(&oflow_acc[(size_t)dstb * DIM + quad * 4 + 0], acc[0]);
                atomicAdd(&oflow_acc[(size_t)dstb * DIM + quad * 4 + 1], acc[1]);
                atomicAdd(&oflow_acc[(size_t)dstb * DIM + quad * 4 + 2], acc[2]);
                atomicAdd(&oflow_acc[(size_t)dstb * DIM + quad * 4 + 3], acc[3]);
            }
        }
    }
}

__device__ __forceinline__ void load_wfrags(
    const float* __restrict__ kern, const float* __restrict__ bias,
    int col, int hb, int j0, frag_ab (&wfrag)[8], frag_ab& bias_a)
{
#pragma unroll
    for (int c = 0; c < 8; ++c) {
        const float* wp = kern + (2 * c + hb) * 256 + col * 16 + j0;
        float4 w0 = *(const float4*)wp;
        float4 w1 = *(const float4*)(wp + 4);
        ABPack p;
        p.u[0] = pack_bf16_2(w0.x, w0.y);
        p.u[1] = pack_bf16_2(w0.z, w0.w);
        p.u[2] = pack_bf16_2(w1.x, w1.y);
        p.u[3] = pack_bf16_2(w1.z, w1.w);
        wfrag[c] = p.f;
    }
    ABPack p; p.u[0] = p.u[1] = p.u[2] = p.u[3] = 0;
    if (hb == 0) {
        const float* bp2 = bias + col * 16 + j0;
        float4 w0 = *(const float4*)bp2;
        float4 w1 = *(const float4*)(bp2 + 4);
        p.u[0] = pack_bf16_2(w0.x, w0.y);
        p.u[1] = pack_bf16_2(w0.z, w0.w);
        p.u[2] = pack_bf16_2(w1.x, w1.y);
        p.u[3] = pack_bf16_2(w1.z, w1.w);
    }
    bias_a = p.f;
}

__device__ __forceinline__ void reduce_one(
    const uint16_t* __restrict__ msgs, const int* __restrict__ counts,
    const float* __restrict__ oflow_acc, float* __restrict__ out, int t)
{
    int a = t >> 5;
    int c = t & 3;
    int q = (t >> 2) & 7;

    int cnt = min(counts[a * CSTR], CAP);
    const uint32_t* base = (const uint32_t*)(msgs + (size_t)a * CAP * DIM);

    float4 acc = make_float4(0.f, 0.f, 0.f, 0.f);
    for (int j = q; j < cnt; j += 8) {
        uint2 v = *(const uint2*)(base + j * 8 + c * 2);
        acc.x += __uint_as_float(v.x << 16);
        acc.y += __uint_as_float(v.x & 0xFFFF0000u);
        acc.z += __uint_as_float(v.y << 16);
        acc.w += __uint_as_float(v.y & 0xFFFF0000u);
    }
    acc.x += __shfl_xor(acc.x, 4);  acc.y += __shfl_xor(acc.y, 4);
    acc.z += __shfl_xor(acc.z, 4);  acc.w += __shfl_xor(acc.w, 4);
    acc.x += __shfl_xor(acc.x, 8);  acc.y += __shfl_xor(acc.y, 8);
    acc.z += __shfl_xor(acc.z, 8);  acc.w += __shfl_xor(acc.w, 8);
    acc.x += __shfl_xor(acc.x, 16); acc.y += __shfl_xor(acc.y, 16);
    acc.z += __shfl_xor(acc.z, 16); acc.w += __shfl_xor(acc.w, 16);
    if (q == 0) {
        float4 oa = *(const float4*)(oflow_acc + (size_t)a * DIM + c * 4);
        acc.x += oa.x; acc.y += oa.y; acc.z += oa.z; acc.w += oa.w;
        ((float4*)(out + (size_t)a * DIM))[c] = acc;
    }
}

// =================== cooperative fused kernel ===================
__global__ __launch_bounds__(256, 4) void fused_kernel(
    const float* __restrict__ atom, const float* __restrict__ bond,
    const int*   __restrict__ pair, const float* __restrict__ kern,
    const float* __restrict__ bias,
    int* __restrict__ counts, float* __restrict__ oflow_acc,
    uint16_t* __restrict__ msgs, float* __restrict__ out,
    int n_edges, int n_groups, int n_atoms)
{
    cg::grid_group grid = cg::this_grid();
    const int tid = blockIdx.x * blockDim.x + threadIdx.x;
    const int NT  = gridDim.x * blockDim.x;

    // ---- phase 0: zero counts + oflow_acc (contiguous 4B words)
    {
        int* ws32 = counts;   // counts then oflow_acc are contiguous
        const int nwords = n_atoms * CSTR + n_atoms * DIM;
        for (int i = tid; i < nwords; i += NT) ws32[i] = 0;
    }
    __threadfence();
    grid.sync();
    __threadfence();

    // ---- phase 1: persistent msg batches
    const int lane = threadIdx.x & 63;
    const int wave = tid >> 6;
    const int NW   = NT >> 6;
    const int col  = lane & 15;
    const int quad = lane >> 4;
    const int hb   = quad >> 1;
    const int j0   = (quad & 1) * 8;

    frag_ab wfrag[8];
    frag_ab bias_a;
    load_wfrags(kern, bias, col, hb, j0, wfrag, bias_a);

    const int NB = (n_groups + GPW - 1) / GPW;
    for (int b = wave; b < NB; b += NW) {
        msg_batch(atom, bond, pair, counts, oflow_acc, msgs, n_edges,
                  b * GPW, lane, col, quad, hb, wfrag, bias_a);
    }
    __threadfence();
    grid.sync();
    __threadfence();

    // ---- phase 2: reduce
    const int rtot = n_atoms * 32;
    for (int t = tid; t < rtot; t += NT)
        reduce_one(msgs, counts, oflow_acc, out, t);
}

// =================== fallback: r12 3-dispatch path ===================
__global__ __launch_bounds__(256, 3) void msg_mfma_kernel(
    const float* __restrict__ atom, const float* __restrict__ bond,
    const int*   __restrict__ pair, const float* __restrict__ kern,
    const float* __restrict__ bias,
    int* __restrict__ counts, float* __restrict__ oflow_acc,
    uint16_t* __restrict__ msgs, int n_edges, int n_groups)
{
    const int wave = (int)((blockIdx.x * blockDim.x + threadIdx.x) >> 6);
    const int lane = threadIdx.x & 63;
    const int g0 = wave * GPW;
    if (g0 >= n_groups) return;
    const int col  = lane & 15;
    const int quad = lane >> 4;
    const int hb   = quad >> 1;
    const int j0   = (quad & 1) * 8;
    frag_ab wfrag[8];
    frag_ab bias_a;
    load_wfrags(kern, bias, col, hb, j0, wfrag, bias_a);
    msg_batch(atom, bond, pair, counts, oflow_acc, msgs, n_edges,
              g0, lane, col, quad, hb, wfrag, bias_a);
}

__global__ __launch_bounds__(256) void reduce_kernel(
    const uint16_t* __restrict__ msgs, const int* __restrict__ counts,
    const float* __restrict__ oflow_acc, float* __restrict__ out, int n_atoms)
{
    int t = blockIdx.x * blockDim.x + threadIdx.x;
    if ((t >> 5) >= n_atoms) return;
    reduce_one(msgs, counts, oflow_acc, out, t);
}

__global__ __launch_bounds__(256) void edge_atomic_kernel(
    const float* __restrict__ atom, const float* __restrict__ bond,
    const int*   __restrict__ pair, const float* __restrict__ kern,
    const float* __restrict__ bias, float* __restrict__ out, int n_edges)
{
    int e = blockIdx.x * blockDim.x + threadIdx.x;
    if (e >= n_edges) return;
    int dst = pair[2 * e + 0];
    int src = pair[2 * e + 1];
    float neigh[DIM], bnd[DIM], acc[DIM];
    for (int q = 0; q < DIM; ++q) neigh[q] = atom[(size_t)src * DIM + q];
    for (int q = 0; q < DIM; ++q) bnd[q]   = bond[(size_t)e * DIM + q];
#pragma unroll
    for (int i = 0; i < DIM; ++i) {
        float d = 0.f;
#pragma unroll
        for (int jj = 0; jj < DIM; ++jj) d = fmaf(bias[i * DIM + jj], neigh[jj], d);
        acc[i] = d;
    }
#pragma unroll 1
    for (int k = 0; k < DIM; ++k) {
        const float bk = bnd[k];
        const float* Kr = kern + k * (DIM * DIM);
#pragma unroll
        for (int i = 0; i < DIM; ++i) {
            float d = 0.f;
#pragma unroll
            for (int jj = 0; jj < DIM; ++jj) d = fmaf(Kr[i * DIM + jj], neigh[jj], d);
            acc[i] = fmaf(bk, d, acc[i]);
        }
    }
#pragma unroll
    for (int i = 0; i < DIM; ++i) atomicAdd(&out[(size_t)dst * DIM + i], acc[i]);
}

extern "C" void kernel_launch(void* const* d_in, const int* in_sizes, int n_in,
                              void* d_out, int out_size, void* d_ws, size_t ws_size,
                              hipStream_t stream)
{
    const float* atom = (const float*)d_in[0];   // (20000,16) f32
    const float* bond = (const float*)d_in[1];   // (640000,16) f32
    const int*   pair = (const int*)d_in[2];     // (640000,2) i32 [dst, src]
    const float* kern = (const float*)d_in[3];   // (16,256) f32
    const float* bias = (const float*)d_in[4];   // (256,) f32
    float*       out  = (float*)d_out;           // (20000,16) f32

    int n_edges = in_sizes[1] / DIM;             // 640000
    int n_atoms = in_sizes[0] / DIM;             // 20000

    // ws: counts[n_atoms*CSTR] | oflow_acc f32[n_atoms*DIM] | msgs bf16
    size_t counts_off = 0;
    size_t oacc_off   = counts_off + (size_t)n_atoms * CSTR * sizeof(int);
    size_t msgs_off   = oacc_off + (size_t)n_atoms * DIM * sizeof(float);
    size_t needed     = msgs_off + (size_t)n_atoms * CAP * DIM * sizeof(uint16_t);

    const int threads = 256;

    if (ws_size >= needed) {
        int*      counts    = (int*)((char*)d_ws + counts_off);
        float*    oflow_acc = (float*)((char*)d_ws + oacc_off);
        uint16_t* msgs      = (uint16_t*)((char*)d_ws + msgs_off);

        int n_groups = (n_edges + 15) / 16;

        // cooperative fused launch: 1024 blocks (4/CU guaranteed co-resident
        // at <=128 VGPR -> 16 waves/CU, vs ~10 measured in split kernels)
        dim3 grid(1024), block(threads);
        void* args[] = { (void*)&atom, (void*)&bond, (void*)&pair,
                         (void*)&kern, (void*)&bias,
                         (void*)&counts, (void*)&oflow_acc, (void*)&msgs,
                         (void*)&out, (void*)&n_edges, (void*)&n_groups,
                         (void*)&n_atoms };
        hipError_t rc = hipLaunchCooperativeKernel(
            (const void*)fused_kernel, grid, block, args, 0, stream);

        if (rc != hipSuccess) {
            // fallback: proven r12 3-dispatch path
            hipMemsetAsync(counts, 0, msgs_off, stream);
            const int waves   = ((n_groups + GPW - 1) / GPW);
            const int mblocks = (waves * 64 + threads - 1) / threads;
            msg_mfma_kernel<<<mblocks, threads, 0, stream>>>(
                atom, bond, pair, kern, bias, counts, oflow_acc, msgs,
                n_edges, n_groups);
            const int rthreads = n_atoms * 32;
            reduce_kernel<<<(rthreads + threads - 1) / threads, threads, 0, stream>>>(
                msgs, counts, oflow_acc, out, n_atoms);
        }
    } else {
        hipMemsetAsync(out, 0, (size_t)out_size * sizeof(float), stream);
        edge_atomic_kernel<<<(n_edges + threads - 1) / threads, threads, 0, stream>>>(
            atom, bond, pair, kern, bias, out, n_edges);
    }
}

// Round 11
// 219.503 us; speedup vs baseline: 2.8256x; 2.8256x over previous
//
#include <hip/hip_runtime.h>
#include <stdint.h>

// EdgeNetwork, round 16: XCD-LOCAL ATOMICS into per-XCD partial buffers.
// r15 post-mortem: cooperative grid.sync spins on system-scope atomics ->
// 536us kernel, dead end. But r14+r15 nailed the mechanism: DEFAULT device-
// scope atomicAdd bypasses the 8 non-coherent per-XCD L2s to the memory-side
// coherence point (r14's 160MB WRITE_SIZE). Fix the SCOPE, not the idea:
// each block reads its physical XCC_ID (HW_REG_XCC_ID, verified on gfx950)
// and accumulates into partial[xcc][dst][16] with relaxed WORKGROUP-scope /
// no-sc pk_add_f32 atomics -> RMW inside the local L2, line stays dirty, no
// write-through. Same-XCD blocks share that L2 (correct serialization);
// cross-XCD blocks use different buffers (no coherence needed); kernel-end
// writeback publishes. sum8 kernel folds 8 partials -> out (11.5MB).
// Deletes: rank atomics, slot logic, 35.8MB msgs buffer + RFO + re-read,
// reduce gather, overflow path. Chain = gather -> MFMA -> fire-and-forget.
// LITMUS: msg WRITE_SIZE must be ~12-16MB. If >=100MB the scope trick failed
// -> revert to r12.
// History: r8/r12 133.0/133.5 (BEST) -> r13 191 -> r14 216 (sc-atomic 160MB)
// -> r15 620 (grid.sync spin). Harness overhead ~60us rides on top of kernels.

constexpr int DIM  = 16;
constexpr int GPW  = 4;      // 16-edge groups per wave, fully unrolled
constexpr int NXCD = 8;

using frag_ab = __attribute__((ext_vector_type(8))) short;   // 8 bf16
using frag_cd = __attribute__((ext_vector_type(4))) float;   // 4 f32
typedef float v2f __attribute__((ext_vector_type(2)));
union ABPack { frag_ab f; uint32_t u[4]; };

__device__ __forceinline__ uint32_t pack_bf16_2(float lo, float hi) {
    return __builtin_amdgcn_perm(__float_as_uint(hi), __float_as_uint(lo), 0x07060302u);
}

__device__ __forceinline__ int get_xcc() {
    int x;
    asm volatile("s_getreg_b32 %0, hwreg(HW_REG_XCC_ID)" : "=s"(x));
    return x & (NXCD - 1);
}

// XCD-local fire-and-forget f32x2 add (no sc bits -> executes in local L2)
__device__ __forceinline__ void l2_atomic_add2(float* p, float a, float b) {
#if __has_builtin(__builtin_amdgcn_global_atomic_fadd_v2f32)
    v2f v = {a, b};
    __builtin_amdgcn_global_atomic_fadd_v2f32((v2f*)p, v);
#else
    __hip_atomic_fetch_add(p + 0, a, __ATOMIC_RELAXED, __HIP_MEMORY_SCOPE_WORKGROUP);
    __hip_atomic_fetch_add(p + 1, b, __ATOMIC_RELAXED, __HIP_MEMORY_SCOPE_WORKGROUP);
#endif
}

// ---- msg kernel: r12 compute path, outputs via XCD-local atomics ----
__global__ __launch_bounds__(256) void msg_part_kernel(
    const float* __restrict__ atom, const float* __restrict__ bond,
    const int*   __restrict__ pair, const float* __restrict__ kern,
    const float* __restrict__ bias, float* __restrict__ partial,
    int n_edges, int n_groups, int n_atoms)
{
    const int wave = (int)((blockIdx.x * blockDim.x + threadIdx.x) >> 6);
    const int lane = threadIdx.x & 63;
    const int g0 = wave * GPW;
    if (g0 >= n_groups) return;

    // per-XCD partial base (wave-uniform SGPR)
    float* pbase = partial + (size_t)get_xcc() * n_atoms * DIM;

    const int col  = lane & 15;        // A(W): output row i | B(Z): edge e | D: col e
    const int quad = lane >> 4;        // 0..3
    const int hb   = quad >> 1;        // k parity within chunk
    const int j0   = (quad & 1) * 8;   // neigh sub-range

    // P1: pair loads (quad0 lanes only)
    int  ec_[GPW];
    int2 pr_[GPW];
#pragma unroll
    for (int u = 0; u < GPW; ++u) {
        const int e = ((g0 + u) << 4) + col;
        ec_[u] = min(e, n_edges - 1);
        pr_[u] = make_int2(0, 0);
        if (quad == 0) pr_[u] = ((const int2*)pair)[ec_[u]];
    }

    // W fragments (L1-hot broadcast; overlaps P1 latency)
    frag_ab wfrag[8];
#pragma unroll
    for (int c = 0; c < 8; ++c) {
        const float* wp = kern + (2 * c + hb) * 256 + col * 16 + j0;
        float4 w0 = *(const float4*)wp;
        float4 w1 = *(const float4*)(wp + 4);
        ABPack p;
        p.u[0] = pack_bf16_2(w0.x, w0.y);
        p.u[1] = pack_bf16_2(w0.z, w0.w);
        p.u[2] = pack_bf16_2(w1.x, w1.y);
        p.u[3] = pack_bf16_2(w1.z, w1.w);
        wfrag[c] = p.f;
    }
    frag_ab bias_a;
    {
        ABPack p; p.u[0] = p.u[1] = p.u[2] = p.u[3] = 0;
        if (hb == 0) {
            const float* bp2 = bias + col * 16 + j0;
            float4 w0 = *(const float4*)bp2;
            float4 w1 = *(const float4*)(bp2 + 4);
            p.u[0] = pack_bf16_2(w0.x, w0.y);
            p.u[1] = pack_bf16_2(w0.z, w0.w);
            p.u[2] = pack_bf16_2(w1.x, w1.y);
            p.u[3] = pack_bf16_2(w1.z, w1.w);
        }
        bias_a = p.f;
    }

    // src broadcast
    int src_[GPW];
#pragma unroll
    for (int u = 0; u < GPW; ++u) src_[u] = __shfl(pr_[u].y, col, 64);

    // P2: dedup gathers. atom chunk cq=[0,2,1,3][quad]; bond chunk `quad`.
    const int cq = ((quad & 1) << 1) | (quad >> 1);
    float4 am_[GPW], bm_[GPW];
#pragma unroll
    for (int u = 0; u < GPW; ++u) {
        am_[u] = *(const float4*)(atom + (size_t)src_[u] * DIM + cq * 4);
        bm_[u] = *(const float4*)(bond + (size_t)ec_[u] * DIM + quad * 4);
    }

    // P4: per group: redistribute + pack + MFMA + local-atomic scatter-add
#pragma unroll
    for (int u = 0; u < GPW; ++u) {
        float4 am = am_[u];
        float4 ao;
        ao.x = __shfl_xor(am.x, 32); ao.y = __shfl_xor(am.y, 32);
        ao.z = __shfl_xor(am.z, 32); ao.w = __shfl_xor(am.w, 32);
        float nb[8];
        nb[0] = quad < 2 ? am.x : ao.x;  nb[1] = quad < 2 ? am.y : ao.y;
        nb[2] = quad < 2 ? am.z : ao.z;  nb[3] = quad < 2 ? am.w : ao.w;
        nb[4] = quad < 2 ? ao.x : am.x;  nb[5] = quad < 2 ? ao.y : am.y;
        nb[6] = quad < 2 ? ao.z : am.z;  nb[7] = quad < 2 ? ao.w : am.w;

        float4 bm = bm_[u];
        float4 bo;
        bo.x = __shfl_xor(bm.x, 16); bo.y = __shfl_xor(bm.y, 16);
        bo.z = __shfl_xor(bm.z, 16); bo.w = __shfl_xor(bm.w, 16);
        float4 cA, cB;
        cA.x = (quad & 1) ? bo.x : bm.x; cA.y = (quad & 1) ? bo.y : bm.y;
        cA.z = (quad & 1) ? bo.z : bm.z; cA.w = (quad & 1) ? bo.w : bm.w;
        cB.x = (quad & 1) ? bm.x : bo.x; cB.y = (quad & 1) ? bm.y : bo.y;
        cB.z = (quad & 1) ? bm.z : bo.z; cB.w = (quad & 1) ? bm.w : bo.w;
        float s0 = hb ? cA.y : cA.x,  s1 = hb ? cA.w : cA.z;
        float s2 = hb ? cB.y : cB.x,  s3 = hb ? cB.w : cB.z;
        float g0v = hb ? cA.x : cA.y, g1v = hb ? cA.z : cA.w;
        float g2v = hb ? cB.x : cB.y, g3v = hb ? cB.z : cB.w;
        float t0 = __shfl_xor(g0v, 32), t1 = __shfl_xor(g1v, 32);
        float t2 = __shfl_xor(g2v, 32), t3 = __shfl_xor(g3v, 32);
        float bks[8];
        bks[0] = quad < 2 ? s0 : t0;  bks[1] = quad < 2 ? s1 : t1;
        bks[2] = quad < 2 ? s2 : t2;  bks[3] = quad < 2 ? s3 : t3;
        bks[4] = quad < 2 ? t0 : s0;  bks[5] = quad < 2 ? t1 : s1;
        bks[6] = quad < 2 ? t2 : s2;  bks[7] = quad < 2 ? t3 : s3;

        frag_cd acc0 = {0.f, 0.f, 0.f, 0.f};
        frag_cd acc1 = {0.f, 0.f, 0.f, 0.f};
#pragma unroll
        for (int c = 0; c < 8; ++c) {
            const float bk = bks[c];
            ABPack z;
            z.u[0] = pack_bf16_2(bk * nb[0], bk * nb[1]);
            z.u[1] = pack_bf16_2(bk * nb[2], bk * nb[3]);
            z.u[2] = pack_bf16_2(bk * nb[4], bk * nb[5]);
            z.u[3] = pack_bf16_2(bk * nb[6], bk * nb[7]);
            if (c & 1)
                acc1 = __builtin_amdgcn_mfma_f32_16x16x32_bf16(wfrag[c], z.f, acc1, 0, 0, 0);
            else
                acc0 = __builtin_amdgcn_mfma_f32_16x16x32_bf16(wfrag[c], z.f, acc0, 0, 0, 0);
        }
        {
            ABPack z; z.u[0] = z.u[1] = z.u[2] = z.u[3] = 0;
            if (hb == 0) {
                z.u[0] = pack_bf16_2(nb[0], nb[1]);
                z.u[1] = pack_bf16_2(nb[2], nb[3]);
                z.u[2] = pack_bf16_2(nb[4], nb[5]);
                z.u[3] = pack_bf16_2(nb[6], nb[7]);
            }
            acc1 = __builtin_amdgcn_mfma_f32_16x16x32_bf16(bias_a, z.f, acc1, 0, 0, 0);
        }
        frag_cd acc = acc0 + acc1;

        // D^T: lane (quad,col) holds msg[e=col][i=quad*4..+3].
        // dst broadcast, then two no-sc pk f32x2 adds into the XCD partial.
        const int dstb = __shfl(pr_[u].x, col, 64);
        const int e    = ((g0 + u) << 4) + col;
        if (e < n_edges) {
            float* row = pbase + (size_t)dstb * DIM + quad * 4;
            l2_atomic_add2(row + 0, acc[0], acc[1]);
            l2_atomic_add2(row + 2, acc[2], acc[3]);
        }
    }
}

// ---- fold 8 partials -> out. 1 thread per float4: 11.5MB traffic.
__global__ __launch_bounds__(256) void sum8_kernel(
    const float* __restrict__ partial, float* __restrict__ out, int n_atoms)
{
    int t = blockIdx.x * blockDim.x + threadIdx.x;
    const int n4 = n_atoms * 4;          // float4 chunks in out
    if (t >= n4) return;
    float4 s = make_float4(0.f, 0.f, 0.f, 0.f);
#pragma unroll
    for (int x = 0; x < NXCD; ++x) {
        float4 v = ((const float4*)(partial + (size_t)x * n_atoms * DIM))[t];
        s.x += v.x; s.y += v.y; s.z += v.z; s.w += v.w;
    }
    ((float4*)out)[t] = s;
}

// ---- safety fallback if ws too small (round-1 structure)
__global__ __launch_bounds__(256) void edge_atomic_kernel(
    const float* __restrict__ atom, const float* __restrict__ bond,
    const int*   __restrict__ pair, const float* __restrict__ kern,
    const float* __restrict__ bias, float* __restrict__ out, int n_edges)
{
    int e = blockIdx.x * blockDim.x + threadIdx.x;
    if (e >= n_edges) return;
    int dst = pair[2 * e + 0];
    int src = pair[2 * e + 1];
    float neigh[DIM], bnd[DIM], acc[DIM];
    for (int q = 0; q < DIM; ++q) neigh[q] = atom[(size_t)src * DIM + q];
    for (int q = 0; q < DIM; ++q) bnd[q]   = bond[(size_t)e * DIM + q];
#pragma unroll
    for (int i = 0; i < DIM; ++i) {
        float d = 0.f;
#pragma unroll
        for (int jj = 0; jj < DIM; ++jj) d = fmaf(bias[i * DIM + jj], neigh[jj], d);
        acc[i] = d;
    }
#pragma unroll 1
    for (int k = 0; k < DIM; ++k) {
        const float bk = bnd[k];
        const float* Kr = kern + k * (DIM * DIM);
#pragma unroll
        for (int i = 0; i < DIM; ++i) {
            float d = 0.f;
#pragma unroll
            for (int jj = 0; jj < DIM; ++jj) d = fmaf(Kr[i * DIM + jj], neigh[jj], d);
            acc[i] = fmaf(bk, d, acc[i]);
        }
    }
#pragma unroll
    for (int i = 0; i < DIM; ++i) atomicAdd(&out[(size_t)dst * DIM + i], acc[i]);
}

extern "C" void kernel_launch(void* const* d_in, const int* in_sizes, int n_in,
                              void* d_out, int out_size, void* d_ws, size_t ws_size,
                              hipStream_t stream)
{
    const float* atom = (const float*)d_in[0];   // (20000,16) f32
    const float* bond = (const float*)d_in[1];   // (640000,16) f32
    const int*   pair = (const int*)d_in[2];     // (640000,2) i32 [dst, src]
    const float* kern = (const float*)d_in[3];   // (16,256) f32
    const float* bias = (const float*)d_in[4];   // (256,) f32
    float*       out  = (float*)d_out;           // (20000,16) f32

    const int n_edges = in_sizes[1] / DIM;       // 640000
    const int n_atoms = in_sizes[0] / DIM;       // 20000

    // ws: partial f32[NXCD][n_atoms][16]  = 10.24 MB
    size_t needed = (size_t)NXCD * n_atoms * DIM * sizeof(float);

    const int threads = 256;

    if (ws_size >= needed) {
        float* partial = (float*)d_ws;

        // zero the 8 partial buffers (10.24 MB)
        hipMemsetAsync(partial, 0, needed, stream);

        const int n_groups = (n_edges + 15) / 16;                  // 40000
        const int waves    = (n_groups + GPW - 1) / GPW;           // 10000
        const int mblocks  = (waves * 64 + threads - 1) / threads; // 2500
        msg_part_kernel<<<mblocks, threads, 0, stream>>>(
            atom, bond, pair, kern, bias, partial, n_edges, n_groups, n_atoms);

        const int sthreads = n_atoms * 4;                          // 80000
        sum8_kernel<<<(sthreads + threads - 1) / threads, threads, 0, stream>>>(
            partial, out, n_atoms);
    } else {
        hipMemsetAsync(out, 0, (size_t)out_size * sizeof(float), stream);
        edge_atomic_kernel<<<(n_edges + threads - 1) / threads, threads, 0, stream>>>(
            atom, bond, pair, kern, bias, out, n_edges);
    }
}